// Round 1
// baseline (92.379 us; speedup 1.0000x reference)
//
#include <hip/hip_runtime.h>

// SWT level-1 (db2, norm=True) along channel axis.
// x: [8, 64, 128, 128] f32 -> out: [8, 128, 128, 128] f32 (cA || cD on axis 1).
// cA[o] = lo3*x[o-1] + lo2*x[o] + lo1*x[o+1] + lo0*x[o+2]  (channels mod 64)
// Memory-bound: 32 MiB in + 64 MiB out. Each thread: one float4 spatial slot,
// 8 output channels -> 11 coalesced float4 loads, 16 coalesced float4 stores.

#define HW4 4096   // (128*128)/4 float4 per channel
#define NC  64     // input channels
#define CH  8      // output channels per block (chunk)

__global__ __launch_bounds__(256) void swt_db2_kernel(
    const float4* __restrict__ x, float4* __restrict__ out) {
  const int s4 = blockIdx.x * 256 + threadIdx.x;   // spatial float4 index
  const int c0 = blockIdx.y * CH;                  // first output channel
  const int b  = blockIdx.z;

  const float4* xb = x  + (size_t)b * NC * HW4 + s4;
  float4*       ob = out + (size_t)b * 2 * NC * HW4 + s4;

  // db2 decomposition filters / sqrt(2)  (pywt order, see header comment)
  const float lo0 = -0.09150635094610966f;
  const float lo1 =  0.15849364905389033f;
  const float lo2 =  0.59150635094610960f;
  const float lo3 =  0.34150635094610970f;
  const float hi0 = -0.34150635094610970f;
  const float hi1 =  0.59150635094610960f;
  const float hi2 = -0.15849364905389033f;
  const float hi3 = -0.09150635094610966f;

  // Load CH+3 = 11 input channels: (c0-1 .. c0+9) mod 64
  float4 v[CH + 3];
#pragma unroll
  for (int k = 0; k < CH + 3; ++k) {
    const int c = (c0 - 1 + k) & (NC - 1);
    v[k] = xb[(size_t)c * HW4];
  }

#pragma unroll
  for (int i = 0; i < CH; ++i) {
    const int o = c0 + i;
    float4 a, d;
    // taps: x[o-1]=v[i], x[o]=v[i+1], x[o+1]=v[i+2], x[o+2]=v[i+3]
#define COMP(f)                                                                 \
    a.f = fmaf(lo3, v[i].f, fmaf(lo2, v[i+1].f,                                 \
           fmaf(lo1, v[i+2].f, lo0 * v[i+3].f)));                               \
    d.f = fmaf(hi3, v[i].f, fmaf(hi2, v[i+1].f,                                 \
           fmaf(hi1, v[i+2].f, hi0 * v[i+3].f)));
    COMP(x) COMP(y) COMP(z) COMP(w)
#undef COMP
    ob[(size_t)o * HW4]        = a;   // cA at channel o
    ob[(size_t)(o + NC) * HW4] = d;   // cD at channel o + 64
  }
}

extern "C" void kernel_launch(void* const* d_in, const int* in_sizes, int n_in,
                              void* d_out, int out_size, void* d_ws, size_t ws_size,
                              hipStream_t stream) {
  const float4* x  = (const float4*)d_in[0];
  float4*       out = (float4*)d_out;
  // grid: x = spatial chunks (4096/256 = 16), y = channel chunks (64/8 = 8), z = batch (8)
  dim3 grid(HW4 / 256, NC / CH, 8);
  dim3 block(256);
  hipLaunchKernelGGL(swt_db2_kernel, grid, block, 0, stream, x, out);
}

// Round 3
// 89.402 us; speedup vs baseline: 1.0333x; 1.0333x over previous
//
#include <hip/hip_runtime.h>

// SWT level-1 (db2, norm=True) along channel axis.
// x: [8, 64, 128, 128] f32 -> out: [8, 128, 128, 128] f32 (cA || cD on axis 1).
// cA[o] = lo3*x[o-1] + lo2*x[o] + lo1*x[o+1] + lo0*x[o+2]  (channels mod 64)
// Memory-bound: 32 MiB in + 64 MiB out (+12 MiB halo re-read) ~ 108 MB -> ~17us floor.
// Each thread: TWO float4 spatial slots x 8 output channels.
//  - 22 coalesced 16B loads (11 channels x 2 slots), 32 nt 16B stores.
//  - nt stores: output is write-once, keep L2 for the input halo reuse.

#define HW4 4096   // (128*128)/4 float4 per channel
#define NC  64     // input channels
#define CH  8      // output channels per block chunk
#define SP  2      // spatial float4 slots per thread

typedef float f4 __attribute__((ext_vector_type(4)));  // native vector: nt-store OK

__global__ __launch_bounds__(256) void swt_db2_kernel(
    const f4* __restrict__ x, f4* __restrict__ out) {
  const int s4 = blockIdx.x * (256 * SP) + threadIdx.x;  // first spatial slot
  const int c0 = blockIdx.y * CH;                        // first output channel
  const int b  = blockIdx.z;

  const f4* xb = x   + (size_t)b * NC * HW4;
  f4*       ob = out + (size_t)b * 2 * NC * HW4;

  const float lo0 = -0.09150635094610966f;
  const float lo1 =  0.15849364905389033f;
  const float lo2 =  0.59150635094610960f;
  const float lo3 =  0.34150635094610970f;
  const float hi0 = -0.34150635094610970f;
  const float hi1 =  0.59150635094610960f;
  const float hi2 = -0.15849364905389033f;
  const float hi3 = -0.09150635094610966f;

  // Load (CH+3) channels x SP slots, all coalesced, issued back-to-back for MLP.
  f4 v[SP][CH + 3];
#pragma unroll
  for (int k = 0; k < CH + 3; ++k) {
    const int c = (c0 - 1 + k) & (NC - 1);
    const f4* p = xb + (size_t)c * HW4 + s4;
#pragma unroll
    for (int m = 0; m < SP; ++m) v[m][k] = p[m * 256];
  }

#pragma unroll
  for (int i = 0; i < CH; ++i) {
    const int o = c0 + i;
#pragma unroll
    for (int m = 0; m < SP; ++m) {
      f4 a, d;
#pragma unroll
      for (int f = 0; f < 4; ++f) {
        a[f] = fmaf(lo3, v[m][i][f], fmaf(lo2, v[m][i+1][f],
                 fmaf(lo1, v[m][i+2][f], lo0 * v[m][i+3][f])));
        d[f] = fmaf(hi3, v[m][i][f], fmaf(hi2, v[m][i+1][f],
                 fmaf(hi1, v[m][i+2][f], hi0 * v[m][i+3][f])));
      }
      __builtin_nontemporal_store(a, ob + (size_t)o * HW4 + s4 + m * 256);
      __builtin_nontemporal_store(d, ob + (size_t)(o + NC) * HW4 + s4 + m * 256);
    }
  }
}

extern "C" void kernel_launch(void* const* d_in, const int* in_sizes, int n_in,
                              void* d_out, int out_size, void* d_ws, size_t ws_size,
                              hipStream_t stream) {
  const f4* x   = (const f4*)d_in[0];
  f4*       out = (f4*)d_out;
  // grid: x = spatial chunks (4096 / (256*SP) = 8), y = channel chunks (8), z = batch (8)
  dim3 grid(HW4 / (256 * SP), NC / CH, 8);
  dim3 block(256);
  hipLaunchKernelGGL(swt_db2_kernel, grid, block, 0, stream, x, out);
}

// Round 4
// 89.231 us; speedup vs baseline: 1.0353x; 1.0019x over previous
//
#include <hip/hip_runtime.h>

// SWT level-1 (db2, norm=True) along channel axis.
// x: [8, 64, 128, 128] f32 -> out: [8, 128, 128, 128] f32 (cA || cD on axis 1).
// cA[o] = lo3*x[o-1] + lo2*x[o] + lo1*x[o+1] + lo0*x[o+2]  (channels mod 64)
// Memory-bound: 32 MiB in + 64 MiB out + halo. CH=16 -> halo = 3/16*32 = 6 MiB
// (was 12 MiB at CH=8). Each thread: one float4 spatial slot x 16 output
// channels: 19 coalesced 16B loads, 32 coalesced nt 16B stores (write-once,
// bypass L2 to preserve it for input halo reuse).

#define HW4 4096   // (128*128)/4 float4 per channel
#define NC  64     // input channels
#define CH  16     // output channels per block chunk

typedef float f4 __attribute__((ext_vector_type(4)));  // native vector: nt-store OK

__global__ __launch_bounds__(256) void swt_db2_kernel(
    const f4* __restrict__ x, f4* __restrict__ out) {
  const int s4 = blockIdx.x * 256 + threadIdx.x;   // spatial float4 slot
  const int c0 = blockIdx.y * CH;                  // first output channel
  const int b  = blockIdx.z;

  const f4* xb = x   + (size_t)b * NC * HW4 + s4;
  f4*       ob = out + (size_t)b * 2 * NC * HW4 + s4;

  const float lo0 = -0.09150635094610966f;
  const float lo1 =  0.15849364905389033f;
  const float lo2 =  0.59150635094610960f;
  const float lo3 =  0.34150635094610970f;
  const float hi0 = -0.34150635094610970f;
  const float hi1 =  0.59150635094610960f;
  const float hi2 = -0.15849364905389033f;
  const float hi3 = -0.09150635094610966f;

  // Load CH+3 = 19 input channels (c0-1 .. c0+17 mod 64), all coalesced,
  // issued back-to-back for memory-level parallelism.
  f4 v[CH + 3];
#pragma unroll
  for (int k = 0; k < CH + 3; ++k) {
    const int c = (c0 - 1 + k) & (NC - 1);
    v[k] = xb[(size_t)c * HW4];
  }

#pragma unroll
  for (int i = 0; i < CH; ++i) {
    const int o = c0 + i;
    f4 a, d;
#pragma unroll
    for (int f = 0; f < 4; ++f) {
      a[f] = fmaf(lo3, v[i][f], fmaf(lo2, v[i+1][f],
               fmaf(lo1, v[i+2][f], lo0 * v[i+3][f])));
      d[f] = fmaf(hi3, v[i][f], fmaf(hi2, v[i+1][f],
               fmaf(hi1, v[i+2][f], hi0 * v[i+3][f])));
    }
    __builtin_nontemporal_store(a, ob + (size_t)o * HW4);
    __builtin_nontemporal_store(d, ob + (size_t)(o + NC) * HW4);
  }
}

extern "C" void kernel_launch(void* const* d_in, const int* in_sizes, int n_in,
                              void* d_out, int out_size, void* d_ws, size_t ws_size,
                              hipStream_t stream) {
  const f4* x   = (const f4*)d_in[0];
  f4*       out = (f4*)d_out;
  // grid: x = spatial chunks (4096/256 = 16), y = channel chunks (64/16 = 4), z = batch (8)
  dim3 grid(HW4 / 256, NC / CH, 8);
  dim3 block(256);
  hipLaunchKernelGGL(swt_db2_kernel, grid, block, 0, stream, x, out);
}